// Round 4
// baseline (66.190 us; speedup 1.0000x reference)
//
#include <hip/hip_runtime.h>
#include <hip/hip_cooperative_groups.h>
#include <stdint.h>

namespace cg = cooperative_groups;

typedef int i32x4 __attribute__((ext_vector_type(4)));
typedef float f32x4 __attribute__((ext_vector_type(4)));
typedef unsigned int u32x2 __attribute__((ext_vector_type(2)));

#define B_DIM 512
#define IN_DIM 1024
#define OUT_DIM 1024
#define APLANE (B_DIM * IN_DIM)       // 524288 bytes per i8 plane
#define WPLANE (OUT_DIM * IN_DIM)     // 1048576 bytes per i8 plane
#define KC 256                        // K-chunk bytes per stage
#define XGROUPS (APLANE / 8)          // 65536
#define TOTGROUPS (XGROUPS + WPLANE / 8)  // 196608

static __device__ __forceinline__ void quant_split(float v, int& hi, int& lo) {
    float t = rintf(v * 4096.0f);              // half-to-even, matches jnp.round
    t = fminf(fmaxf(t, -32768.0f), 32767.0f);
    int q = (int)t;
    lo = ((q + 128) & 255) - 128;              // centered low byte [-128,127]
    hi = (q - lo) >> 8;                        // [-128,127] for this data (|q|<32640)
}

// One 8-element quant/split item: item < XGROUPS -> x group, else w group.
static __device__ __forceinline__ void prep_one(int item,
                                                const float* __restrict__ x,
                                                const float* __restrict__ w,
                                                signed char* __restrict__ A8,
                                                signed char* __restrict__ W8) {
    bool isx = item < XGROUPS;
    int g = isx ? item : item - XGROUPS;
    const float* src = isx ? x : w;
    signed char* hiP = (isx ? A8 : W8) + (size_t)g * 8;
    signed char* loP = hiP + (isx ? APLANE : WPLANE);

    f32x4 v0 = ((const f32x4*)src)[g * 2];
    f32x4 v1 = ((const f32x4*)src)[g * 2 + 1];

    unsigned char hb[8], lb[8];
#pragma unroll
    for (int j = 0; j < 4; ++j) {
        int hi, lo;
        quant_split(v0[j], hi, lo);
        hb[j] = (unsigned char)hi; lb[j] = (unsigned char)lo;
        quant_split(v1[j], hi, lo);
        hb[4 + j] = (unsigned char)hi; lb[4 + j] = (unsigned char)lo;
    }
    *(u32x2*)hiP = *(const u32x2*)hb;
    *(u32x2*)loP = *(const u32x2*)lb;
}

// Single cooperative kernel: prep -> grid.sync -> exact int8 GEMM + requant + bias.
// GEMM: C[b,o] = 65536*hh + 256*(hl+lh) + ll over full K=1024 per block.
// 32x32 tile -> 512 blocks (2/CU). 4 waves, one 16x16 quadrant each.
// K staged in 4 double-buffered chunks; 16B slots XOR-swizzled (phys = s ^ (row&7))
// via pre-swizzled global source (global_load_lds dest stays linear).
__global__ __launch_bounds__(256, 2) void fused_kernel(const float* __restrict__ x,
                                                       const float* __restrict__ w,
                                                       const float* __restrict__ bias,
                                                       float* __restrict__ out,
                                                       signed char* __restrict__ A8,
                                                       signed char* __restrict__ W8) {
    __shared__ signed char sA[2][16384];
    __shared__ signed char sB[2][16384];

    // ---- Phase A: quantize/split (each thread 1-2 items, 196608 total) ----
    int tid = blockIdx.x * 256 + threadIdx.x;   // [0, 131072)
    prep_one(tid, x, w, A8, W8);
    if (tid < TOTGROUPS - 131072)               // first 65536 threads take a 2nd item
        prep_one(tid + 131072, x, w, A8, W8);

    cg::this_grid().sync();                     // device-scope fence + grid barrier

    // ---- Phase B: fused GEMM ----
    // XCD-ownership swizzle: XCD (bid&7) owns n-blocks 4x..4x+3 (exclusive W slice).
    int bid = blockIdx.x;
    int idx = bid >> 3;
    int nblk = (bid & 7) * 4 + (idx & 3);
    int mblk = idx >> 2;
    int m0 = mblk * 32, n0 = nblk * 32;

    int t = threadIdx.x;
    int lane = t & 63;
    int wv = t >> 6;
    int wm = wv >> 1, wn = wv & 1;

    auto stage = [&](int c, int buf) {
#pragma unroll
        for (int i = 0; i < 4; ++i) {
            int sidx = i * 256 + t;            // 16B slot: [plane][row][s]
            int p = sidx >> 9;
            int row = (sidx >> 4) & 31;
            int s = sidx & 15;
            int ssw = s ^ (row & 7);
            const signed char* ga = A8 + (size_t)p * APLANE + (size_t)(m0 + row) * IN_DIM + c * KC + ssw * 16;
            __builtin_amdgcn_global_load_lds(
                (const __attribute__((address_space(1))) void*)ga,
                (__attribute__((address_space(3))) void*)&sA[buf][sidx * 16], 16, 0, 0);
            const signed char* gb = W8 + (size_t)p * WPLANE + (size_t)(n0 + row) * IN_DIM + c * KC + ssw * 16;
            __builtin_amdgcn_global_load_lds(
                (const __attribute__((address_space(1))) void*)gb,
                (__attribute__((address_space(3))) void*)&sB[buf][sidx * 16], 16, 0, 0);
        }
    };

    i32x4 hh = {}, mid = {}, ll = {};
    int arow = wm * 16 + (lane & 15);
    int brow = wn * 16 + (lane & 15);

    stage(0, 0);
    __syncthreads();

    int buf = 0;
    for (int c = 0; c < 4; ++c) {
        if (c < 3) stage(c + 1, buf ^ 1);
#pragma unroll
        for (int k4 = 0; k4 < 4; ++k4) {
            int aphys = (k4 * 4 + (lane >> 4)) ^ (arow & 7);
            int bphys = (k4 * 4 + (lane >> 4)) ^ (brow & 7);
            i32x4 a0 = *(const i32x4*)&sA[buf][arow * 256 + aphys * 16];
            i32x4 a1 = *(const i32x4*)&sA[buf][8192 + arow * 256 + aphys * 16];
            i32x4 b0 = *(const i32x4*)&sB[buf][brow * 256 + bphys * 16];
            i32x4 b1 = *(const i32x4*)&sB[buf][8192 + brow * 256 + bphys * 16];
            hh  = __builtin_amdgcn_mfma_i32_16x16x64_i8(a0, b0, hh, 0, 0, 0);
            mid = __builtin_amdgcn_mfma_i32_16x16x64_i8(a0, b1, mid, 0, 0, 0);
            mid = __builtin_amdgcn_mfma_i32_16x16x64_i8(a1, b0, mid, 0, 0, 0);
            ll  = __builtin_amdgcn_mfma_i32_16x16x64_i8(a1, b1, ll, 0, 0, 0);
        }
        __syncthreads();                        // also drains vmcnt (next chunk ready)
        buf ^= 1;
    }

    // Epilogue: exact combine, requantize, bias. C/D: col=lane&15, row=(lane>>4)*4+j
    int gcol = n0 + wn * 16 + (lane & 15);
    int grow0 = m0 + wm * 16 + ((lane >> 4) << 2);
    float bv = bias[gcol];
#pragma unroll
    for (int j = 0; j < 4; ++j) {
        int s = hh[j] * 65536 + mid[j] * 256 + ll[j];   // exact int32 acc
        double q = rint((double)s * 0x1p-12);           // round(acc*2^-12), exact
        q = q < -32768.0 ? -32768.0 : (q > 32767.0 ? 32767.0 : q);
        out[(size_t)(grow0 + j) * OUT_DIM + gcol] = (float)(q * 0x1p-12) + bv;
    }
}

extern "C" void kernel_launch(void* const* d_in, const int* in_sizes, int n_in,
                              void* d_out, int out_size, void* d_ws, size_t ws_size,
                              hipStream_t stream) {
    const float* x = (const float*)d_in[0];
    const float* w = (const float*)d_in[1];
    const float* bias = (const float*)d_in[2];
    float* out = (float*)d_out;

    signed char* A8 = (signed char*)d_ws;                // 1 MB
    signed char* W8 = (signed char*)d_ws + (1u << 20);   // 2 MB

    void* args[] = {(void*)&x, (void*)&w, (void*)&bias, (void*)&out,
                    (void*)&A8, (void*)&W8};
    hipLaunchCooperativeKernel((const void*)fused_kernel, dim3(512), dim3(256),
                               args, 0, stream);
}

// Round 5
// 16.782 us; speedup vs baseline: 3.9442x; 3.9442x over previous
//
#include <hip/hip_runtime.h>
#include <stdint.h>

typedef int i32x4 __attribute__((ext_vector_type(4)));
typedef float f32x4 __attribute__((ext_vector_type(4)));
typedef unsigned int u32x4 __attribute__((ext_vector_type(4)));

#define B_DIM 512
#define IN_DIM 1024
#define OUT_DIM 1024
#define TM 64
#define TN 32
#define KC 256          // original-k elements per chunk (4 chunks)

// Single fused kernel: per-block direct quantization (f32 -> int16 -> hi/lo i8
// planes, packed in-register) into LDS, then exact int8 MFMA GEMM + requantize
// + bias. No global barrier, no intermediate global buffers.
//
// LDS per buffer: A [2 planes][64 rows][256 B] = 32 KB, B [2][32][256] = 16 KB.
// Double-buffered: 96 KB total -> 1 block/CU, 256 blocks = 256 CUs.
// 16B slots XOR-swizzled: phys = slot ^ (row&7), applied on ds_write and ds_read.
__global__ __launch_bounds__(256, 1) void fused_kernel(const float* __restrict__ x,
                                                       const float* __restrict__ w,
                                                       const float* __restrict__ bias,
                                                       float* __restrict__ out) {
    __shared__ signed char sA[2][2 * 64 * 256];   // [buf][plane*16384 + row*256 + b]
    __shared__ signed char sB[2][2 * 32 * 256];   // [buf][plane*8192  + row*256 + b]

    // XCD-ownership swizzle: XCD (bid&7) owns n-blocks 4x..4x+3 (128 W rows).
    int bid = blockIdx.x;
    int nblk = (bid & 7) * 4 + ((bid >> 3) & 3);
    int mblk = bid >> 5;
    int m0 = mblk * TM, n0 = nblk * TN;

    int t = threadIdx.x;
    int lane = t & 63;
    int wv = t >> 6;

    // ---- chunk load: 6 items/thread (4 A + 2 B), 16 f32 each ----
    auto loadc = [&](int c, f32x4 (&v)[6][4]) {
#pragma unroll
        for (int i = 0; i < 4; ++i) {
            int item = i * 256 + t;
            int row = item >> 4, g = item & 15;
            const f32x4* p = (const f32x4*)(x + (size_t)(m0 + row) * IN_DIM + c * KC + g * 16);
#pragma unroll
            for (int j = 0; j < 4; ++j) v[i][j] = p[j];
        }
#pragma unroll
        for (int i = 0; i < 2; ++i) {
            int item = i * 256 + t;
            int row = item >> 4, g = item & 15;
            const f32x4* p = (const f32x4*)(w + (size_t)(n0 + row) * IN_DIM + c * KC + g * 16);
#pragma unroll
            for (int j = 0; j < 4; ++j) v[4 + i][j] = p[j];
        }
    };

    // ---- quantize + byte-pack + swizzled ds_write ----
    // tq = rndne(v*4096 + 128); q = tq-128 = 256*hi + lo with lo in [-128,127]:
    // hi byte = tq>>8 (arith), lo byte = (tq & 255) ^ 0x80.
    auto writec = [&](int buf, f32x4 (&v)[6][4]) {
#pragma unroll
        for (int i = 0; i < 6; ++i) {
            const bool isA = i < 4;
            int item = (isA ? i : i - 4) * 256 + t;
            int row = item >> 4, g = item & 15;
            unsigned int hw[4], lw[4];
#pragma unroll
            for (int j = 0; j < 4; ++j) {
                unsigned int tq[4];
#pragma unroll
                for (int e = 0; e < 4; ++e)
                    tq[e] = (unsigned int)(int)rintf(fmaf(v[i][j][e], 4096.0f, 128.0f));
                unsigned p01h = __builtin_amdgcn_perm(tq[1], tq[0], 0x00000501u);
                unsigned p23h = __builtin_amdgcn_perm(tq[3], tq[2], 0x00000501u);
                hw[j] = __builtin_amdgcn_perm(p23h, p01h, 0x05040100u);
                unsigned p01l = __builtin_amdgcn_perm(tq[1], tq[0], 0x00000400u);
                unsigned p23l = __builtin_amdgcn_perm(tq[3], tq[2], 0x00000400u);
                lw[j] = __builtin_amdgcn_perm(p23l, p01l, 0x05040100u) ^ 0x80808080u;
            }
            signed char* base = isA ? &sA[buf][0] : &sB[buf][0];
            int planeStride = isA ? 16384 : 8192;
            int off = row * 256 + ((g ^ (row & 7)) * 16);
            *(u32x4*)(base + off) = *(const u32x4*)hw;                 // plane0 = hi
            *(u32x4*)(base + planeStride + off) = *(const u32x4*)lw;   // plane1 = lo
        }
    };

    // ---- MFMA: wave wv owns rows wv*16..+15 of the 64-row tile, all 32 cols ----
    i32x4 hh[2] = {}, mid[2] = {}, ll[2] = {};
    int arow = wv * 16 + (lane & 15);

    auto compute = [&](int buf) {
#pragma unroll
        for (int k4 = 0; k4 < 4; ++k4) {
            int slot = ((k4 * 4 + (lane >> 4)) ^ (lane & 7)) * 16;  // arow&7 == brow&7 == lane&7
            i32x4 a0 = *(const i32x4*)&sA[buf][arow * 256 + slot];
            i32x4 a1 = *(const i32x4*)&sA[buf][16384 + arow * 256 + slot];
#pragma unroll
            for (int nq = 0; nq < 2; ++nq) {
                int brow = nq * 16 + (lane & 15);
                i32x4 b0 = *(const i32x4*)&sB[buf][brow * 256 + slot];
                i32x4 b1 = *(const i32x4*)&sB[buf][8192 + brow * 256 + slot];
                hh[nq]  = __builtin_amdgcn_mfma_i32_16x16x64_i8(a0, b0, hh[nq], 0, 0, 0);
                mid[nq] = __builtin_amdgcn_mfma_i32_16x16x64_i8(a0, b1, mid[nq], 0, 0, 0);
                mid[nq] = __builtin_amdgcn_mfma_i32_16x16x64_i8(a1, b0, mid[nq], 0, 0, 0);
                ll[nq]  = __builtin_amdgcn_mfma_i32_16x16x64_i8(a1, b1, ll[nq], 0, 0, 0);
            }
        }
    };

    // ---- pipeline: load c+1 early, MFMA on c, quant+write c+1 late ----
    {
        f32x4 v0[6][4];
        loadc(0, v0);
        writec(0, v0);
    }
    __syncthreads();

    int buf = 0;
    for (int c = 0; c < 4; ++c) {
        f32x4 vn[6][4];
        if (c < 3) loadc(c + 1, vn);     // global loads in flight during MFMA
        compute(buf);
        if (c < 3) writec(buf ^ 1, vn);  // quant + ds_write after MFMA issue
        __syncthreads();
        buf ^= 1;
    }

    // ---- epilogue: exact combine, requantize, bias ----
    // C/D layout: col = lane&15, row = (lane>>4)*4 + j
    int grow0 = m0 + wv * 16 + ((lane >> 4) << 2);
#pragma unroll
    for (int nq = 0; nq < 2; ++nq) {
        int gcol = n0 + nq * 16 + (lane & 15);
        float bv = bias[gcol];
#pragma unroll
        for (int j = 0; j < 4; ++j) {
            int s = hh[nq][j] * 65536 + mid[nq][j] * 256 + ll[nq][j];  // exact int32
            double q = rint((double)s * 0x1p-12);                       // exact round
            q = q < -32768.0 ? -32768.0 : (q > 32767.0 ? 32767.0 : q);
            out[(size_t)(grow0 + j) * OUT_DIM + gcol] = (float)(q * 0x1p-12) + bv;
        }
    }
}

extern "C" void kernel_launch(void* const* d_in, const int* in_sizes, int n_in,
                              void* d_out, int out_size, void* d_ws, size_t ws_size,
                              hipStream_t stream) {
    const float* x = (const float*)d_in[0];
    const float* w = (const float*)d_in[1];
    const float* bias = (const float*)d_in[2];
    float* out = (float*)d_out;

    fused_kernel<<<256, 256, 0, stream>>>(x, w, bias, out);
}

// Round 7
// 14.448 us; speedup vs baseline: 4.5813x; 1.1615x over previous
//
#include <hip/hip_runtime.h>
#include <stdint.h>

typedef int i32x4 __attribute__((ext_vector_type(4)));
typedef float f32x4 __attribute__((ext_vector_type(4)));
typedef unsigned int u32x4 __attribute__((ext_vector_type(4)));

#define B_DIM 512
#define IN_DIM 1024
#define OUT_DIM 1024
#define TM 64
#define TN 32
#define KC 256          // original-k elements per chunk (4 chunks)

// Single fused kernel, 512 threads (8 waves) per block, 256 blocks (1/CU,
// 2 waves/SIMD). Direct quantization f32 -> int16 -> hi/lo i8 planes packed
// in-register (magic-constant round) into swizzled LDS, exact int8 MFMA GEMM,
// exact requantize + bias.
//
// LDS per buffer: A [2 planes][64][256B] = 32 KB, B [2][32][256B] = 16 KB.
// Double-buffered: 96 KB. 16B slots XOR-swizzled: phys = slot ^ (row&7).
__global__ __launch_bounds__(512, 1) void fused_kernel(const float* __restrict__ x,
                                                       const float* __restrict__ w,
                                                       const float* __restrict__ bias,
                                                       float* __restrict__ out) {
    __shared__ signed char sA[2][2 * 64 * 256];   // [buf][plane*16384 + row*256 + b]
    __shared__ signed char sB[2][2 * 32 * 256];   // [buf][plane*8192  + row*256 + b]

    // XCD-ownership swizzle: XCD (bid&7) owns n-blocks 4x..4x+3 (128 W rows).
    int bid = blockIdx.x;
    int nblk = (bid & 7) * 4 + ((bid >> 3) & 3);
    int mblk = bid >> 5;
    int m0 = mblk * TM, n0 = nblk * TN;

    int t = threadIdx.x;
    int lane = t & 63;
    int wv = t >> 6;            // 8 waves: 4 m-quadrants x 2 n-quadrants
    int wm = wv >> 1, wn = wv & 1;

    // ---- chunk load: 3 items/thread (2 A + 1 B), 16 f32 each ----
    auto loadc = [&](int c, f32x4 (&v)[3][4]) {
#pragma unroll
        for (int i = 0; i < 2; ++i) {
            int item = i * 512 + t;
            int row = item >> 4, g = item & 15;
            const f32x4* p = (const f32x4*)(x + (size_t)(m0 + row) * IN_DIM + c * KC + g * 16);
#pragma unroll
            for (int j = 0; j < 4; ++j) v[i][j] = p[j];
        }
        {
            int row = t >> 4, g = t & 15;
            const f32x4* p = (const f32x4*)(w + (size_t)(n0 + row) * IN_DIM + c * KC + g * 16);
#pragma unroll
            for (int j = 0; j < 4; ++j) v[2][j] = p[j];
        }
    };

    // ---- magic-quant + byte-pack + swizzled ds_write ----
    // t = RN(v*4096 + 2^23 + 2^22 + 128): ulp=1, single round, half-even.
    // stored int = 2^23 + 2^22 + (q + 128), q = round(v*4096)
    // mantissa byte0 = (q+128)&255  -> ^0x80 = centered lo in [-128,127]
    // mantissa byte1 = (q+128)>>8 & 255 = hi  (q = 256*hi + lo exactly)
    auto writec = [&](int buf, f32x4 (&v)[3][4]) {
        const float MAGIC = 12583040.0f;           // 2^23 + 2^22 + 128  (NOT 12583168)
#pragma unroll
        for (int i = 0; i < 3; ++i) {
            const bool isA = i < 2;
            int item = isA ? (i * 512 + t) : t;
            int row = item >> 4, g = item & 15;
            unsigned int hw[4], lw[4];
#pragma unroll
            for (int j = 0; j < 4; ++j) {
                unsigned int tb[4];
#pragma unroll
                for (int e = 0; e < 4; ++e)
                    tb[e] = __builtin_bit_cast(unsigned int,
                                fmaf(v[i][j][e], 4096.0f, MAGIC));
                unsigned p01h = __builtin_amdgcn_perm(tb[1], tb[0], 0x00000501u);
                unsigned p23h = __builtin_amdgcn_perm(tb[3], tb[2], 0x00000501u);
                hw[j] = __builtin_amdgcn_perm(p23h, p01h, 0x05040100u);
                unsigned p01l = __builtin_amdgcn_perm(tb[1], tb[0], 0x00000400u);
                unsigned p23l = __builtin_amdgcn_perm(tb[3], tb[2], 0x00000400u);
                lw[j] = __builtin_amdgcn_perm(p23l, p01l, 0x05040100u) ^ 0x80808080u;
            }
            signed char* base = isA ? &sA[buf][0] : &sB[buf][0];
            int planeStride = isA ? 16384 : 8192;
            int off = row * 256 + ((g ^ (row & 7)) * 16);
            *(u32x4*)(base + off) = *(const u32x4*)hw;                 // plane0 = hi
            *(u32x4*)(base + planeStride + off) = *(const u32x4*)lw;   // plane1 = lo
        }
    };

    // ---- MFMA: wave (wm,wn) owns 16x16 quadrant ----
    i32x4 hh = {}, mid = {}, ll = {};
    int arow = wm * 16 + (lane & 15);
    int brow = wn * 16 + (lane & 15);

    auto compute = [&](int buf) {
#pragma unroll
        for (int k4 = 0; k4 < 4; ++k4) {
            int slot = ((k4 * 4 + (lane >> 4)) ^ (lane & 7)) * 16;  // arow&7==brow&7==lane&7
            i32x4 a0 = *(const i32x4*)&sA[buf][arow * 256 + slot];
            i32x4 a1 = *(const i32x4*)&sA[buf][16384 + arow * 256 + slot];
            i32x4 b0 = *(const i32x4*)&sB[buf][brow * 256 + slot];
            i32x4 b1 = *(const i32x4*)&sB[buf][8192 + brow * 256 + slot];
            hh  = __builtin_amdgcn_mfma_i32_16x16x64_i8(a0, b0, hh, 0, 0, 0);
            mid = __builtin_amdgcn_mfma_i32_16x16x64_i8(a0, b1, mid, 0, 0, 0);
            mid = __builtin_amdgcn_mfma_i32_16x16x64_i8(a1, b0, mid, 0, 0, 0);
            ll  = __builtin_amdgcn_mfma_i32_16x16x64_i8(a1, b1, ll, 0, 0, 0);
        }
    };

    // ---- pipeline: load c+1 early, MFMA on c, quant+write c+1 late ----
    {
        f32x4 v0[3][4];
        loadc(0, v0);
        writec(0, v0);
    }
    __syncthreads();

#pragma unroll
    for (int c = 0; c < 4; ++c) {
        int buf = c & 1;
        f32x4 vn[3][4];
        if (c < 3) loadc(c + 1, vn);     // global loads in flight during MFMA
        compute(buf);
        if (c < 3) writec(buf ^ 1, vn);  // quant + ds_write after MFMA issue
        __syncthreads();
    }

    // ---- epilogue: exact combine, requantize, bias ----
    // C/D layout: col = lane&15, row = (lane>>4)*4 + j
    int grow0 = m0 + wm * 16 + ((lane >> 4) << 2);
    int gcol = n0 + wn * 16 + (lane & 15);
    float bv = bias[gcol];
#pragma unroll
    for (int j = 0; j < 4; ++j) {
        int s = hh[j] * 65536 + mid[j] * 256 + ll[j];   // exact int32 acc
        double q = rint((double)s * 0x1p-12);           // exact round(acc*2^-12)
        q = q < -32768.0 ? -32768.0 : (q > 32767.0 ? 32767.0 : q);
        out[(size_t)(grow0 + j) * OUT_DIM + gcol] = (float)(q * 0x1p-12) + bv;
    }
}

extern "C" void kernel_launch(void* const* d_in, const int* in_sizes, int n_in,
                              void* d_out, int out_size, void* d_ws, size_t ws_size,
                              hipStream_t stream) {
    const float* x = (const float*)d_in[0];
    const float* w = (const float*)d_in[1];
    const float* bias = (const float*)d_in[2];
    float* out = (float*)d_out;

    fused_kernel<<<256, 512, 0, stream>>>(x, w, bias, out);
}

// Round 8
// 11.879 us; speedup vs baseline: 5.5720x; 1.2163x over previous
//
#include <hip/hip_runtime.h>
#include <stdint.h>

typedef int i32x4 __attribute__((ext_vector_type(4)));
typedef float f32x4 __attribute__((ext_vector_type(4)));
typedef unsigned int u32x2 __attribute__((ext_vector_type(2)));
typedef unsigned int u32x4 __attribute__((ext_vector_type(4)));

#define B_DIM 512
#define IN_DIM 1024
#define OUT_DIM 1024
#define TM 64
#define TN 32
#define KC 128          // original-k elements per chunk (8 chunks)

// Single fused kernel, 512 threads (8 waves), 256 blocks (1/CU, 2 waves/SIMD).
// f32 -> int16 -> hi/lo i8 planes via one magic-fma per element, byte-packed
// with v_perm, staged in XOR-swizzled double-buffered LDS, exact int8 MFMA
// GEMM (hh/mid/ll paths), exact requantize + bias.
//
// Schedule: 8 K-chunks, depth-2 register prefetch, quant/ds_write of chunk
// c+1 overlapped with MFMA of chunk c, s_setprio around MFMA clusters.
// LDS: A [2][2 planes][64][128B] = 32 KB, B [2][2][32][128B] = 16 KB.
// 16B slots XOR-swizzled: phys = slot ^ (row&7) on both write and read.
struct Chunk { f32x4 a[4]; f32x4 b[2]; };

__global__ __launch_bounds__(512, 1) void fused_kernel(const float* __restrict__ x,
                                                       const float* __restrict__ w,
                                                       const float* __restrict__ bias,
                                                       float* __restrict__ out) {
    __shared__ signed char sA[2][16384];   // [buf][plane*8192 + row*128 + b]
    __shared__ signed char sB[2][8192];    // [buf][plane*4096 + row*128 + b]

    // XCD-ownership swizzle: XCD (bid&7) owns n-blocks 4x..4x+3 (128 W rows).
    int bid = blockIdx.x;
    int nblk = (bid & 7) * 4 + ((bid >> 3) & 3);
    int mblk = bid >> 5;
    int m0 = mblk * TM, n0 = nblk * TN;

    int t = threadIdx.x;
    int lane = t & 63;
    int wv = t >> 6;            // 8 waves: 4 m-quadrants x 2 n-quadrants
    int wm = wv >> 1, wn = wv & 1;

    // A: thread t -> row t>>3 (0..63), 16B-slot t&7 (16 f32).
    // B: thread t -> row t>>4 (0..31), 8B-half t&15 (8 f32).
    int aRow = t >> 3, aG = t & 7;
    int bRow = t >> 4, bG = t & 15;
    const float* aSrc = x + (size_t)(m0 + aRow) * IN_DIM + aG * 16;
    const float* bSrc = w + (size_t)(n0 + bRow) * IN_DIM + bG * 8;
    int aOff = aRow * 128 + ((aG ^ (aRow & 7)) * 16);
    int bOff = bRow * 128 + (((bG >> 1) ^ (bRow & 7)) * 16) + (bG & 1) * 8;

    auto loadc = [&](int c, Chunk& v) {
        const f32x4* pa = (const f32x4*)(aSrc + c * KC);
#pragma unroll
        for (int j = 0; j < 4; ++j) v.a[j] = pa[j];
        const f32x4* pb = (const f32x4*)(bSrc + c * KC);
#pragma unroll
        for (int j = 0; j < 2; ++j) v.b[j] = pb[j];
    };

    // magic-quant: t = RN(v*4096 + 2^23+2^22+128), ulp=1 half-even.
    // mantissa byte0 = (q+128)&255 -> ^0x80 = centered lo; byte1 = hi.
    const float MAGIC = 12583040.0f;       // 2^23 + 2^22 + 128
    auto writec = [&](int buf, Chunk& v) {
        unsigned int hwA[4], lwA[4];
#pragma unroll
        for (int j = 0; j < 4; ++j) {
            unsigned int tb[4];
#pragma unroll
            for (int e = 0; e < 4; ++e)
                tb[e] = __builtin_bit_cast(unsigned int, fmaf(v.a[j][e], 4096.0f, MAGIC));
            unsigned p01h = __builtin_amdgcn_perm(tb[1], tb[0], 0x00000501u);
            unsigned p23h = __builtin_amdgcn_perm(tb[3], tb[2], 0x00000501u);
            hwA[j] = __builtin_amdgcn_perm(p23h, p01h, 0x05040100u);
            unsigned p01l = __builtin_amdgcn_perm(tb[1], tb[0], 0x00000400u);
            unsigned p23l = __builtin_amdgcn_perm(tb[3], tb[2], 0x00000400u);
            lwA[j] = __builtin_amdgcn_perm(p23l, p01l, 0x05040100u) ^ 0x80808080u;
        }
        *(u32x4*)&sA[buf][aOff] = *(const u32x4*)hwA;          // plane0 = hi
        *(u32x4*)&sA[buf][8192 + aOff] = *(const u32x4*)lwA;   // plane1 = lo

        unsigned int hwB[2], lwB[2];
#pragma unroll
        for (int j = 0; j < 2; ++j) {
            unsigned int tb[4];
#pragma unroll
            for (int e = 0; e < 4; ++e)
                tb[e] = __builtin_bit_cast(unsigned int, fmaf(v.b[j][e], 4096.0f, MAGIC));
            unsigned p01h = __builtin_amdgcn_perm(tb[1], tb[0], 0x00000501u);
            unsigned p23h = __builtin_amdgcn_perm(tb[3], tb[2], 0x00000501u);
            hwB[j] = __builtin_amdgcn_perm(p23h, p01h, 0x05040100u);
            unsigned p01l = __builtin_amdgcn_perm(tb[1], tb[0], 0x00000400u);
            unsigned p23l = __builtin_amdgcn_perm(tb[3], tb[2], 0x00000400u);
            lwB[j] = __builtin_amdgcn_perm(p23l, p01l, 0x05040100u) ^ 0x80808080u;
        }
        *(u32x2*)&sB[buf][bOff] = *(const u32x2*)hwB;
        *(u32x2*)&sB[buf][4096 + bOff] = *(const u32x2*)lwB;
    };

    i32x4 hh = {}, mid = {}, ll = {};
    int arow = wm * 16 + (lane & 15);
    int brow = wn * 16 + (lane & 15);

    auto compute = [&](int buf) {
        __builtin_amdgcn_s_setprio(1);
#pragma unroll
        for (int k4 = 0; k4 < 2; ++k4) {
            int slot = ((k4 * 4 + (lane >> 4)) ^ (lane & 7)) * 16;  // arow&7==brow&7==lane&7
            i32x4 a0 = *(const i32x4*)&sA[buf][arow * 128 + slot];
            i32x4 a1 = *(const i32x4*)&sA[buf][8192 + arow * 128 + slot];
            i32x4 b0 = *(const i32x4*)&sB[buf][brow * 128 + slot];
            i32x4 b1 = *(const i32x4*)&sB[buf][4096 + brow * 128 + slot];
            hh  = __builtin_amdgcn_mfma_i32_16x16x64_i8(a0, b0, hh, 0, 0, 0);
            mid = __builtin_amdgcn_mfma_i32_16x16x64_i8(a0, b1, mid, 0, 0, 0);
            mid = __builtin_amdgcn_mfma_i32_16x16x64_i8(a1, b0, mid, 0, 0, 0);
            ll  = __builtin_amdgcn_mfma_i32_16x16x64_i8(a1, b1, ll, 0, 0, 0);
        }
        __builtin_amdgcn_s_setprio(0);
    };

    // ---- pipeline: depth-2 prefetch, write-late, 8 chunks ----
    Chunk v0, v1;
    loadc(0, v0);
    loadc(1, v1);
    writec(0, v0);
    __syncthreads();

#pragma unroll
    for (int c = 0; c < 8; ++c) {
        Chunk& vfree = (c & 1) ? v1 : v0;   // held chunk c (already in LDS)
        Chunk& vnext = (c & 1) ? v0 : v1;   // holds chunk c+1
        if (c < 6) loadc(c + 2, vfree);     // loads in flight across this phase
        compute(c & 1);
        if (c < 7) writec((c + 1) & 1, vnext);
        if (c < 7) __syncthreads();
    }

    // ---- epilogue: exact combine, requantize, bias ----
    // C/D layout: col = lane&15, row = (lane>>4)*4 + j
    int grow0 = m0 + wm * 16 + ((lane >> 4) << 2);
    int gcol = n0 + wn * 16 + (lane & 15);
    float bv = bias[gcol];
#pragma unroll
    for (int j = 0; j < 4; ++j) {
        int s = hh[j] * 65536 + mid[j] * 256 + ll[j];   // exact int32 acc
        double q = rint((double)s * 0x1p-12);           // exact round(acc*2^-12)
        q = q < -32768.0 ? -32768.0 : (q > 32767.0 ? 32767.0 : q);
        out[(size_t)(grow0 + j) * OUT_DIM + gcol] = (float)(q * 0x1p-12) + bv;
    }
}

extern "C" void kernel_launch(void* const* d_in, const int* in_sizes, int n_in,
                              void* d_out, int out_size, void* d_ws, size_t ws_size,
                              hipStream_t stream) {
    const float* x = (const float*)d_in[0];
    const float* w = (const float*)d_in[1];
    const float* bias = (const float*)d_in[2];
    float* out = (float*)d_out;

    fused_kernel<<<256, 512, 0, stream>>>(x, w, bias, out);
}